// Round 5
// baseline (180.322 us; speedup 1.0000x reference)
//
#include <hip/hip_runtime.h>
#include <hip/hip_bf16.h>
#include <stdint.h>

// Problem constants: B=8, T=2048, C=1024 (n_embd), H=128 (head dim)
#define BB 8
#define TT 2048
#define CC 1024
#define HH 128
#define VTP 2112      // Vt row pitch (u16): 4224 B, breaks 4 KB set-aliasing

typedef __attribute__((ext_vector_type(8))) short bf16x8;
typedef __attribute__((ext_vector_type(8))) unsigned short u16x8;
typedef __attribute__((ext_vector_type(4))) float f32x4;
typedef __attribute__((ext_vector_type(8))) _Float16 h16x8;

static __device__ __forceinline__ unsigned short f2bf(float f) {
    union { float f; uint32_t u; } v; v.f = f;
    return (unsigned short)((v.u + 0x7fffu + ((v.u >> 16) & 1u)) >> 16);  // RNE
}

#define GLOBAL_AS __attribute__((address_space(1)))
#define LDS_AS    __attribute__((address_space(3)))
static __device__ __forceinline__ void async16(const void* g, void* l) {
    // global->LDS DMA, 16 B/lane; LDS dest = wave-uniform base + lane*16
    __builtin_amdgcn_global_load_lds((const GLOBAL_AS void*)g, (LDS_AS void*)l, 16, 0, 0);
}

// ---------------------------------------------------------------------------
// Kernel 0: W fp32 [k][n] -> bf16 Wb [3*128 n][1024 k]  (k-contiguous rows)
// ---------------------------------------------------------------------------
__global__ __launch_bounds__(256) void wconv(
    const float* __restrict__ Wq, const float* __restrict__ Wk,
    const float* __restrict__ Wv, unsigned short* __restrict__ Wb)
{
    int u = blockIdx.x * 256 + threadIdx.x;
    if (u >= 3 * 128 * 128) return;
    int kc = u & 127, n = (u >> 7) & 127, mat = u >> 14;
    const float* W = (mat == 0) ? Wq : (mat == 1) ? Wk : Wv;
    const float* s = W + (size_t)(kc * 8) * HH + n;
    u16x8 v;
    #pragma unroll
    for (int j = 0; j < 8; j++) v[j] = f2bf(s[(size_t)j * HH]);
    *(u16x8*)(Wb + ((size_t)mat * HH + n) * CC + kc * 8) = v;
}

// ---------------------------------------------------------------------------
// Kernel 1: fused QKV projection. BM=64, 512 threads (8 waves = 2 m-halves x
// 4 n-quarters, each 32m x 96n, 24 MFMA/step), grid 256. BK=64, XOR-swizzled
// Bs via async16; x reg-prefetch after barrier. Unchanged this round.
// ---------------------------------------------------------------------------
#define BS_U16 4608              // As = 64 rows * 72 pitch
#define EQ_OFF 0
#define EK_OFF 8704
#define EV_OFF 17408
__global__ __launch_bounds__(512) void qkv_proj(
    const float* __restrict__ x, const unsigned short* __restrict__ Wb,
    unsigned short* __restrict__ Q, unsigned short* __restrict__ K,
    unsigned short* __restrict__ Vt)
{
    __shared__ __align__(16) unsigned short lds[29184];   // 58.37 KB

    const int m0  = blockIdx.x * 64;
    const int tid = threadIdx.x;
    const int lane = tid & 63;
    const int w    = tid >> 6;       // 0..7
    const int qd   = lane >> 4;
    const int ln   = lane & 15;
    const int wm   = w & 1;          // m half (32 rows)
    const int wn   = w >> 1;         // n quarter (96 cols)

    f32x4 acc[2][6];
    #pragma unroll
    for (int i = 0; i < 2; i++)
        #pragma unroll
        for (int j = 0; j < 6; j++) acc[i][j] = (f32x4){0.f,0.f,0.f,0.f};

    const int xr = tid >> 3;         // 0..63 row
    const int xg = (tid & 7) * 8;    // col offset (8 floats / thread)

    float4 xf[2];
    {
        const float* s = x + (size_t)(m0 + xr) * CC + xg;
        xf[0] = ((const float4*)s)[0];
        xf[1] = ((const float4*)s)[1];
    }

    for (int k0 = 0; k0 < CC; k0 += 64) {
        {
            u16x8 v0;
            v0[0]=f2bf(xf[0].x); v0[1]=f2bf(xf[0].y); v0[2]=f2bf(xf[0].z); v0[3]=f2bf(xf[0].w);
            v0[4]=f2bf(xf[1].x); v0[5]=f2bf(xf[1].y); v0[6]=f2bf(xf[1].z); v0[7]=f2bf(xf[1].w);
            *(u16x8*)&lds[xr * 72 + xg] = v0;
        }
        // Bs: 384 rows x 64 k (bf16), 16B chunks, XOR swizzle (^row&7).
        // 3072 chunks / 512 lanes = 6 async16 rounds.
        #pragma unroll
        for (int i = 0; i < 6; i++) {
            int sb = i * 512 + w * 64;
            int slot = sb + lane;
            int row = slot >> 3, j = (slot & 7) ^ (row & 7);
            async16(Wb + (size_t)row * CC + k0 + j * 8, &lds[BS_U16 + sb * 8]);
        }
        __syncthreads();
        // x prefetch for next step: issued here so its HBM latency drains
        // at the trailing barrier (under the MFMA phase).
        if (k0 + 64 < CC) {
            const float* s = x + (size_t)(m0 + xr) * CC + k0 + 64 + xg;
            xf[0] = ((const float4*)s)[0];
            xf[1] = ((const float4*)s)[1];
        }
        #pragma unroll
        for (int ks = 0; ks < 2; ks++) {
            bf16x8 a0 = *(const bf16x8*)&lds[(wm*32 + ln) * 72 + ks*32 + qd*8];
            bf16x8 a1 = *(const bf16x8*)&lds[(wm*32 + 16 + ln) * 72 + ks*32 + qd*8];
            #pragma unroll
            for (int nf = 0; nf < 6; nf++) {
                int row = wn * 96 + nf * 16 + ln;
                int ch  = (ks * 4 + qd) ^ (row & 7);
                bf16x8 b = *(const bf16x8*)&lds[BS_U16 + (row * 8 + ch) * 8];
                acc[0][nf] = __builtin_amdgcn_mfma_f32_16x16x32_bf16(a0, b, acc[0][nf], 0, 0, 0);
                acc[1][nf] = __builtin_amdgcn_mfma_f32_16x16x32_bf16(a1, b, acc[1][nf], 0, 0, 0);
            }
        }
        __syncthreads();
    }

    // epilogue: scatter acc -> LDS (Q/K row-major pitch 136; V transposed pitch 72)
    #pragma unroll
    for (int mf = 0; mf < 2; mf++)
        #pragma unroll
        for (int nf = 0; nf < 6; nf++) {
            int n = wn * 96 + nf * 16;
            int mat = n >> 7, hb = n & 127;
            #pragma unroll
            for (int r = 0; r < 4; r++) {
                unsigned short v = f2bf(acc[mf][nf][r]);
                int mrow = wm*32 + mf*16 + qd*4 + r;       // 0..63
                if (mat < 2) lds[(mat ? EK_OFF : EQ_OFF) + mrow * 136 + hb + ln] = v;
                else         lds[EV_OFF + (hb + ln) * 72 + mrow] = v;
            }
        }
    __syncthreads();
    {
        int rr = tid >> 3, c0 = (tid & 7) * 16;            // 64 rows x 8 thr
        #pragma unroll
        for (int i = 0; i < 2; i++) {
            u16x8 vq = *(const u16x8*)&lds[EQ_OFF + rr * 136 + c0 + i * 8];
            *(u16x8*)(Q + (size_t)(m0 + rr) * HH + c0 + i * 8) = vq;
            u16x8 vk = *(const u16x8*)&lds[EK_OFF + rr * 136 + c0 + i * 8];
            *(u16x8*)(K + (size_t)(m0 + rr) * HH + c0 + i * 8) = vk;
        }
    }
    {
        int bb = m0 >> 11, t0 = m0 & (TT - 1);
        int hh = tid >> 2, tf = (tid & 3) * 16;            // 128 h x 4 thr
        #pragma unroll
        for (int i = 0; i < 2; i++) {
            u16x8 vv = *(const u16x8*)&lds[EV_OFF + hh * 72 + tf + i * 8];
            *(u16x8*)(Vt + ((size_t)bb * HH + hh) * VTP + t0 + tf + i * 8) = vv;
        }
    }
}

// ---------------------------------------------------------------------------
// Kernel 2: flash attention (causal), no-max softmax.
// R11 restructure: K/V are L2-resident (512/540 KB per batch) -- LDS staging
// was pure overhead (2 barriers + 64 KB DMA drain per step dominated; all
// pipes <45%; cf. learn_hip m169: dropping V staging at L2-fit sizes +26%).
// Now K and V fragments are loaded DIRECTLY from global (same 16B/lane
// fragment pattern, no swizzle, no DMA, ZERO barriers in the main loop).
// Waves run fully decoupled; P round-trip stays in same-wave private LDS.
// Block = 32 q-rows, 512 thr, 8 waves = (qgrp x2: 16 q) x (kq4 x4: 32 keys).
// LDS 43.5 KB (P + merge only) -> 2 blocks/CU, 4 waves/SIMD.
// Complementary tile pairing (qt_l+qt_s=63) retained. 4-way merge at end.
// ---------------------------------------------------------------------------
__global__ __launch_bounds__(512) void attn(
    const unsigned short* __restrict__ Q, const unsigned short* __restrict__ K,
    const unsigned short* __restrict__ Vt, float* __restrict__ out)
{
    __shared__ __align__(16) _Float16 Om[8][16 * 128];       // 32 KB merge buffer
    __shared__ __align__(16) unsigned short Ps[8][16 * 40];  // 10 KB, per-wave P
    __shared__ float Lp[8][16];

    const int tid  = threadIdx.x;
    const int lane = tid & 63;
    const int wave = tid >> 6;            // 0..7
    const int qd = lane >> 4;
    const int ln = lane & 15;
    const int qgrp = wave >> 2;           // 0: q rows 0-15, 1: rows 16-31
    const int kq4  = wave & 3;            // key quarter (32 keys)

    const int bx = blockIdx.x;
    int b, qt;
    if (bx < 256) { b = bx & 7;               qt = 63 - (bx >> 3); }  // long, desc
    else          { int u = bx - 256; b = u & 7; qt = u >> 3; }       // short, asc
    const int qbase = qt * 32 + qgrp * 16;
    const int nst = (qt + 4) >> 2;        // 128-key steps; nst*128 <= 2048 always

    const unsigned short* Qb = Q  + (size_t)b * TT * HH;
    const unsigned short* Kb = K  + (size_t)b * TT * HH;
    const unsigned short* Vb = Vt + (size_t)b * HH * VTP;

    bf16x8 aq[4];
    #pragma unroll
    for (int c = 0; c < 4; c++)
        aq[c] = *(const bf16x8*)(Qb + (size_t)(qbase + ln) * HH + c * 32 + qd * 8);

    f32x4 O[8];
    float lsum[4];
    #pragma unroll
    for (int h = 0; h < 8; h++) O[h] = (f32x4){0.f,0.f,0.f,0.f};
    #pragma unroll
    for (int r = 0; r < 4; r++) lsum[r] = 0.f;

    const float sl   = 0.08838834764831843f * 1.4426950408889634f; // (1/sqrt128)*log2e
    const float M0L2 = 7.2134752044448f;                           // 5.0*log2(e)
    unsigned short* ps = Ps[wave];

    for (int st = 0; st < nst; st++) {
        const int s0 = st * 128;

        // ---- S = Q K^T : 16 q x 32 keys; K fragments direct from global.
        //      Lane ln = key row (s0 + kq4*32 + nt*16 + ln), 16B chunk
        //      (c*4+qd) within the 256B row. All 8 loads independent. ----
        f32x4 s[2] = {(f32x4){0.f,0.f,0.f,0.f}, (f32x4){0.f,0.f,0.f,0.f}};
        #pragma unroll
        for (int nt = 0; nt < 2; nt++) {
            const unsigned short* kr = Kb + (size_t)(s0 + kq4*32 + nt*16 + ln) * HH;
            #pragma unroll
            for (int c = 0; c < 4; c++) {
                bf16x8 bk = *(const bf16x8*)(kr + (c*4 + qd) * 8);
                s[nt] = __builtin_amdgcn_mfma_f32_16x16x32_bf16(aq[c], bk, s[nt], 0, 0, 0);
            }
        }
        // ---- exp2 + causal mask; per-lane l; P -> private LDS (pitch 40) ----
        #pragma unroll
        for (int nt = 0; nt < 2; nt++) {
            int col = s0 + kq4 * 32 + nt * 16 + ln;
            #pragma unroll
            for (int r = 0; r < 4; r++) {
                int row = qbase + qd * 4 + r;
                float e = __builtin_amdgcn_exp2f(s[nt][r] * sl - M0L2);
                e = (col <= row) ? e : 0.f;
                lsum[r] += e;
                ps[(qd*4 + r) * 40 + nt*16 + ln] = f2bf(e);
            }
        }
        // ---- P in A-layout (own slice; same-wave DS is in-order) ----
        bf16x8 ap = *(const bf16x8*)&ps[ln * 40 + qd * 8];
        // ---- O += P V over this wave's 32 keys; V fragments direct from
        //      global Vt[h][keys]: lane ln = h row (ht*16+ln), keys
        //      s0 + kq4*32 + qd*8. 8 independent loads. ----
        #pragma unroll
        for (int ht = 0; ht < 8; ht++) {
            bf16x8 bv = *(const bf16x8*)(Vb + (size_t)(ht*16 + ln) * VTP + s0 + kq4*32 + qd*8);
            O[ht] = __builtin_amdgcn_mfma_f32_16x16x32_bf16(ap, bv, O[ht], 0, 0, 0);
        }
    }

    // ---- end: l reduce over ln lanes; O (fp16) into merge buffer ----
    #pragma unroll
    for (int r = 0; r < 4; r++) {
        float sum = lsum[r];
        #pragma unroll
        for (int off = 1; off < 16; off <<= 1)
            sum += __shfl_xor(sum, off, 64);
        if (ln == 0) Lp[wave][qd*4 + r] = sum;
    }
    _Float16* om = &Om[wave][0];
    #pragma unroll
    for (int ht = 0; ht < 8; ht++)
        #pragma unroll
        for (int r = 0; r < 4; r++)
            om[(qd*4 + r) * 128 + ht*16 + ln] = (_Float16)O[ht][r];
    __syncthreads();

    // ---- 4-way merge (key quarters) + write: 32 rows x 16 thr, 8 h each ----
    {
        int row = tid >> 4, h0 = (tid & 15) * 8;
        int g = row >> 4, q = row & 15;
        float L = Lp[g*4 + 0][q] + Lp[g*4 + 1][q] + Lp[g*4 + 2][q] + Lp[g*4 + 3][q];
        float inv = 1.0f / L;
        const _Float16* p0 = &Om[g*4 + 0][q * 128 + h0];
        const _Float16* p1 = &Om[g*4 + 1][q * 128 + h0];
        const _Float16* p2 = &Om[g*4 + 2][q * 128 + h0];
        const _Float16* p3 = &Om[g*4 + 3][q * 128 + h0];
        float* op = out + ((size_t)b * TT + qt * 32 + row) * HH + h0;
        #pragma unroll
        for (int i = 0; i < 2; i++) {
            float4 v;
            v.x = (((float)p0[i*4+0] + (float)p1[i*4+0]) + ((float)p2[i*4+0] + (float)p3[i*4+0])) * inv;
            v.y = (((float)p0[i*4+1] + (float)p1[i*4+1]) + ((float)p2[i*4+1] + (float)p3[i*4+1])) * inv;
            v.z = (((float)p0[i*4+2] + (float)p1[i*4+2]) + ((float)p2[i*4+2] + (float)p3[i*4+2])) * inv;
            v.w = (((float)p0[i*4+3] + (float)p1[i*4+3]) + ((float)p2[i*4+3] + (float)p3[i*4+3])) * inv;
            ((float4*)op)[i] = v;
        }
    }
}

// ---------------------------------------------------------------------------
extern "C" void kernel_launch(void* const* d_in, const int* in_sizes, int n_in,
                              void* d_out, int out_size, void* d_ws, size_t ws_size,
                              hipStream_t stream) {
    const float* x  = (const float*)d_in[0];
    const float* Wq = (const float*)d_in[1];
    const float* Wk = (const float*)d_in[2];
    const float* Wv = (const float*)d_in[3];

    // workspace (u16): Wb [384][1024]; Q,K [16384][128]; Vt [8][128][VTP]
    unsigned short* Wb = (unsigned short*)d_ws;
    unsigned short* Qw = Wb + (size_t)3 * HH * CC;
    unsigned short* Kw = Qw + (size_t)BB * TT * HH;
    unsigned short* Vw = Kw + (size_t)BB * TT * HH;

    wconv<<<dim3(192), 256, 0, stream>>>(Wq, Wk, Wv, Wb);
    qkv_proj<<<dim3(256), 512, 0, stream>>>(x, Wb, Qw, Kw, Vw);
    attn<<<dim3(512), 512, 0, stream>>>(Qw, Kw, Vw, (float*)d_out);
}

// Round 6
// 148.809 us; speedup vs baseline: 1.2118x; 1.2118x over previous
//
#include <hip/hip_runtime.h>
#include <hip/hip_bf16.h>
#include <stdint.h>

// Problem constants: B=8, T=2048, C=1024 (n_embd), H=128 (head dim)
#define BB 8
#define TT 2048
#define CC 1024
#define HH 128
#define VTP 2112      // Vt row pitch (u16): 4224 B, breaks 4 KB set-aliasing

typedef __attribute__((ext_vector_type(8))) short bf16x8;
typedef __attribute__((ext_vector_type(8))) unsigned short u16x8;
typedef __attribute__((ext_vector_type(4))) float f32x4;
typedef __attribute__((ext_vector_type(8))) _Float16 h16x8;

static __device__ __forceinline__ unsigned short f2bf(float f) {
    union { float f; uint32_t u; } v; v.f = f;
    return (unsigned short)((v.u + 0x7fffu + ((v.u >> 16) & 1u)) >> 16);  // RNE
}

#define GLOBAL_AS __attribute__((address_space(1)))
#define LDS_AS    __attribute__((address_space(3)))
static __device__ __forceinline__ void async16(const void* g, void* l) {
    // global->LDS DMA, 16 B/lane; LDS dest = wave-uniform base + lane*16
    __builtin_amdgcn_global_load_lds((const GLOBAL_AS void*)g, (LDS_AS void*)l, 16, 0, 0);
}

// ---------------------------------------------------------------------------
// Kernel 0: W fp32 [k][n] -> bf16 Wb [3*128 n][1024 k]  (k-contiguous rows)
// ---------------------------------------------------------------------------
__global__ __launch_bounds__(256) void wconv(
    const float* __restrict__ Wq, const float* __restrict__ Wk,
    const float* __restrict__ Wv, unsigned short* __restrict__ Wb)
{
    int u = blockIdx.x * 256 + threadIdx.x;
    if (u >= 3 * 128 * 128) return;
    int kc = u & 127, n = (u >> 7) & 127, mat = u >> 14;
    const float* W = (mat == 0) ? Wq : (mat == 1) ? Wk : Wv;
    const float* s = W + (size_t)(kc * 8) * HH + n;
    u16x8 v;
    #pragma unroll
    for (int j = 0; j < 8; j++) v[j] = f2bf(s[(size_t)j * HH]);
    *(u16x8*)(Wb + ((size_t)mat * HH + n) * CC + kc * 8) = v;
}

// ---------------------------------------------------------------------------
// Kernel 1: fused QKV projection. BM=64, 512 threads (8 waves = 2 m-halves x
// 4 n-quarters, each 32m x 96n, 24 MFMA/step), grid 256. BK=64, XOR-swizzled
// Bs via async16; x reg-prefetch after barrier. Unchanged this round.
// ---------------------------------------------------------------------------
#define BS_U16 4608              // As = 64 rows * 72 pitch
#define EQ_OFF 0
#define EK_OFF 8704
#define EV_OFF 17408
__global__ __launch_bounds__(512) void qkv_proj(
    const float* __restrict__ x, const unsigned short* __restrict__ Wb,
    unsigned short* __restrict__ Q, unsigned short* __restrict__ K,
    unsigned short* __restrict__ Vt)
{
    __shared__ __align__(16) unsigned short lds[29184];   // 58.37 KB

    const int m0  = blockIdx.x * 64;
    const int tid = threadIdx.x;
    const int lane = tid & 63;
    const int w    = tid >> 6;       // 0..7
    const int qd   = lane >> 4;
    const int ln   = lane & 15;
    const int wm   = w & 1;          // m half (32 rows)
    const int wn   = w >> 1;         // n quarter (96 cols)

    f32x4 acc[2][6];
    #pragma unroll
    for (int i = 0; i < 2; i++)
        #pragma unroll
        for (int j = 0; j < 6; j++) acc[i][j] = (f32x4){0.f,0.f,0.f,0.f};

    const int xr = tid >> 3;         // 0..63 row
    const int xg = (tid & 7) * 8;    // col offset (8 floats / thread)

    float4 xf[2];
    {
        const float* s = x + (size_t)(m0 + xr) * CC + xg;
        xf[0] = ((const float4*)s)[0];
        xf[1] = ((const float4*)s)[1];
    }

    for (int k0 = 0; k0 < CC; k0 += 64) {
        {
            u16x8 v0;
            v0[0]=f2bf(xf[0].x); v0[1]=f2bf(xf[0].y); v0[2]=f2bf(xf[0].z); v0[3]=f2bf(xf[0].w);
            v0[4]=f2bf(xf[1].x); v0[5]=f2bf(xf[1].y); v0[6]=f2bf(xf[1].z); v0[7]=f2bf(xf[1].w);
            *(u16x8*)&lds[xr * 72 + xg] = v0;
        }
        // Bs: 384 rows x 64 k (bf16), 16B chunks, XOR swizzle (^row&7).
        // 3072 chunks / 512 lanes = 6 async16 rounds.
        #pragma unroll
        for (int i = 0; i < 6; i++) {
            int sb = i * 512 + w * 64;
            int slot = sb + lane;
            int row = slot >> 3, j = (slot & 7) ^ (row & 7);
            async16(Wb + (size_t)row * CC + k0 + j * 8, &lds[BS_U16 + sb * 8]);
        }
        __syncthreads();
        // x prefetch for next step: issued here so its HBM latency drains
        // at the trailing barrier (under the MFMA phase).
        if (k0 + 64 < CC) {
            const float* s = x + (size_t)(m0 + xr) * CC + k0 + 64 + xg;
            xf[0] = ((const float4*)s)[0];
            xf[1] = ((const float4*)s)[1];
        }
        #pragma unroll
        for (int ks = 0; ks < 2; ks++) {
            bf16x8 a0 = *(const bf16x8*)&lds[(wm*32 + ln) * 72 + ks*32 + qd*8];
            bf16x8 a1 = *(const bf16x8*)&lds[(wm*32 + 16 + ln) * 72 + ks*32 + qd*8];
            #pragma unroll
            for (int nf = 0; nf < 6; nf++) {
                int row = wn * 96 + nf * 16 + ln;
                int ch  = (ks * 4 + qd) ^ (row & 7);
                bf16x8 b = *(const bf16x8*)&lds[BS_U16 + (row * 8 + ch) * 8];
                acc[0][nf] = __builtin_amdgcn_mfma_f32_16x16x32_bf16(a0, b, acc[0][nf], 0, 0, 0);
                acc[1][nf] = __builtin_amdgcn_mfma_f32_16x16x32_bf16(a1, b, acc[1][nf], 0, 0, 0);
            }
        }
        __syncthreads();
    }

    // epilogue: scatter acc -> LDS (Q/K row-major pitch 136; V transposed pitch 72)
    #pragma unroll
    for (int mf = 0; mf < 2; mf++)
        #pragma unroll
        for (int nf = 0; nf < 6; nf++) {
            int n = wn * 96 + nf * 16;
            int mat = n >> 7, hb = n & 127;
            #pragma unroll
            for (int r = 0; r < 4; r++) {
                unsigned short v = f2bf(acc[mf][nf][r]);
                int mrow = wm*32 + mf*16 + qd*4 + r;       // 0..63
                if (mat < 2) lds[(mat ? EK_OFF : EQ_OFF) + mrow * 136 + hb + ln] = v;
                else         lds[EV_OFF + (hb + ln) * 72 + mrow] = v;
            }
        }
    __syncthreads();
    {
        int rr = tid >> 3, c0 = (tid & 7) * 16;            // 64 rows x 8 thr
        #pragma unroll
        for (int i = 0; i < 2; i++) {
            u16x8 vq = *(const u16x8*)&lds[EQ_OFF + rr * 136 + c0 + i * 8];
            *(u16x8*)(Q + (size_t)(m0 + rr) * HH + c0 + i * 8) = vq;
            u16x8 vk = *(const u16x8*)&lds[EK_OFF + rr * 136 + c0 + i * 8];
            *(u16x8*)(K + (size_t)(m0 + rr) * HH + c0 + i * 8) = vk;
        }
    }
    {
        int bb = m0 >> 11, t0 = m0 & (TT - 1);
        int hh = tid >> 2, tf = (tid & 3) * 16;            // 128 h x 4 thr
        #pragma unroll
        for (int i = 0; i < 2; i++) {
            u16x8 vv = *(const u16x8*)&lds[EV_OFF + hh * 72 + tf + i * 8];
            *(u16x8*)(Vt + ((size_t)bb * HH + hh) * VTP + t0 + tf + i * 8) = vv;
        }
    }
}

// ---------------------------------------------------------------------------
// Kernel 2: flash attention (causal), no-max softmax.
// R12: revert R11's direct-global loads (16-line gathers through L1 were a
// 2x regression). Back to LDS staging, restructured around the measured
// invariant: R8/R9/R10 all cost ~2500-3000 cy per barrier interval per CU,
// additive across co-resident blocks. So: FEWER, FATTER intervals with
// prefetch. QBLK=64 q-rows, KVBLK=128, DOUBLE-buffered K/V, 1024 threads
// (16 waves = 4 qgrp x 4 kq; per-wave step shape identical to R10:
// 16q x 32k, 8 QK-MFMA, 8 exp2, P round-trip, 8 PV-MFMA, same swizzles).
// R8-style schedule: ONE barrier/step; STAGE(st+1) issued right after the
// barrier so its 64 KB DMA completes under the compute phase (syncthreads
// makes each wave drain its own DMAs before signaling -> safe).
// Intervals/CU: 34 -> nst = (qt+2)>>1 <= 16. Grid 256 = 1 block/CU
// (LDS 149 KB dynamic, 4 waves/SIMD). bx&7 = batch spreads qt over XCDs.
// ---------------------------------------------------------------------------
__global__ __launch_bounds__(1024) void attn(
    const unsigned short* __restrict__ Q, const unsigned short* __restrict__ K,
    const unsigned short* __restrict__ Vt, float* __restrict__ out)
{
    extern __shared__ __align__(16) unsigned short dyn[];
    unsigned short* KsB = dyn;               // [2][128*128] 64 KB (merge overlay)
    unsigned short* VsB = dyn + 32768;       // [2][128*128] 64 KB
    unsigned short* PsB = dyn + 65536;       // [16][16*40]  20 KB
    float*          Lp  = (float*)(dyn + 75776);  // [16][16]  1 KB   (total 149 KB)

    const int tid  = threadIdx.x;
    const int lane = tid & 63;
    const int wave = tid >> 6;            // 0..15
    const int qd = lane >> 4;
    const int ln = lane & 15;
    const int qgrp = wave >> 2;           // 0..3: q rows qgrp*16..+16
    const int kq   = wave & 3;            // key quarter (32 keys of 128)

    const int bx = blockIdx.x;
    const int b  = bx & 7;                // batch varies fastest -> XCD spread
    const int qt = bx >> 3;               // 0..31, QBLK=64
    const int qbase = qt * 64 + qgrp * 16;
    const int nst = (qt + 2) >> 1;        // 128-key steps; nst*128 <= 2048

    const unsigned short* Qb = Q  + (size_t)b * TT * HH;
    const unsigned short* Kb = K  + (size_t)b * TT * HH;
    const unsigned short* Vb = Vt + (size_t)b * HH * VTP;

    bf16x8 aq[4];
    #pragma unroll
    for (int c = 0; c < 4; c++)
        aq[c] = *(const bf16x8*)(Qb + (size_t)(qbase + ln) * HH + c * 32 + qd * 8);

    f32x4 O[8];
    float lsum[4];
    #pragma unroll
    for (int h = 0; h < 8; h++) O[h] = (f32x4){0.f,0.f,0.f,0.f};
    #pragma unroll
    for (int r = 0; r < 4; r++) lsum[r] = 0.f;

    const float sl   = 0.08838834764831843f * 1.4426950408889634f; // (1/sqrt128)*log2e
    const float M0L2 = 7.2134752044448f;                           // 5.0*log2(e)
    unsigned short* ps = PsB + wave * 640;

    // ---- staging: K 128 rows x 16 chunks, V 128 h x 16 chunks; XOR ^row&15;
    //      2048 chunks each / 1024 lanes = 2 async16 rounds each ----
    #define STAGE(S0, BUF)                                                              \
        do {                                                                            \
            _Pragma("unroll")                                                           \
            for (int i = 0; i < 2; i++) {                                               \
                int sb = i * 1024 + wave * 64;                                          \
                int slot = sb + lane;                                                   \
                int row = slot >> 4, jj = (slot & 15) ^ (row & 15);                     \
                async16(Kb + (size_t)((S0) + row) * HH + jj * 8,                        \
                        KsB + (size_t)(BUF) * 16384 + sb * 8);                          \
            }                                                                           \
            _Pragma("unroll")                                                           \
            for (int i = 0; i < 2; i++) {                                               \
                int sb = i * 1024 + wave * 64;                                          \
                int slot = sb + lane;                                                   \
                int row = slot >> 4, jj = (slot & 15) ^ (row & 15);                     \
                async16(Vb + (size_t)row * VTP + (S0) + jj * 8,                         \
                        VsB + (size_t)(BUF) * 16384 + sb * 8);                          \
            }                                                                           \
        } while (0)

    STAGE(0, 0);
    for (int st = 0; st < nst; st++) {
        __syncthreads();                  // drains prev STAGE (each wave drains own DMAs)
        if (st + 1 < nst) STAGE((st + 1) * 128, (st + 1) & 1);
        const int buf = st & 1;
        const unsigned short* Ks = KsB + (size_t)buf * 16384;
        const unsigned short* Vs = VsB + (size_t)buf * 16384;
        const int s0 = st * 128;

        // ---- S = Q K^T : 16 q x 32 keys (this wave's quarter) ----
        f32x4 s[2] = {(f32x4){0.f,0.f,0.f,0.f}, (f32x4){0.f,0.f,0.f,0.f}};
        #pragma unroll
        for (int nt = 0; nt < 2; nt++) {
            int krow = kq * 32 + nt * 16;      // +ln = key within step; row&15 == ln
            #pragma unroll
            for (int c = 0; c < 4; c++) {
                bf16x8 bk = *(const bf16x8*)&Ks[(krow + ln) * 128 + (((c*4 + qd) ^ ln)) * 8];
                s[nt] = __builtin_amdgcn_mfma_f32_16x16x32_bf16(aq[c], bk, s[nt], 0, 0, 0);
            }
        }
        // ---- exp2 + causal mask; per-lane l; P -> private LDS (pitch 40) ----
        #pragma unroll
        for (int nt = 0; nt < 2; nt++) {
            int col = s0 + kq * 32 + nt * 16 + ln;
            #pragma unroll
            for (int r = 0; r < 4; r++) {
                int row = qbase + qd * 4 + r;
                float e = __builtin_amdgcn_exp2f(s[nt][r] * sl - M0L2);
                e = (col <= row) ? e : 0.f;
                lsum[r] += e;
                ps[(qd*4 + r) * 40 + nt*16 + ln] = f2bf(e);
            }
        }
        // ---- P in A-layout (own slice; same-wave DS is in-order) ----
        bf16x8 ap = *(const bf16x8*)&ps[ln * 40 + qd * 8];
        // ---- O += P V over this wave's 32 keys, all 128 h ----
        #pragma unroll
        for (int ht = 0; ht < 8; ht++) {
            int vrow = ht * 16 + ln;           // vrow&15 == ln
            bf16x8 bv = *(const bf16x8*)&Vs[vrow * 128 + (((kq*4 + qd) ^ ln)) * 8];
            O[ht] = __builtin_amdgcn_mfma_f32_16x16x32_bf16(ap, bv, O[ht], 0, 0, 0);
        }
    }

    // ---- end: l reduce over ln lanes; O (fp16) into merge buffer (Ks overlay) ----
    __syncthreads();                      // all waves done with Ks/Vs
    #pragma unroll
    for (int r = 0; r < 4; r++) {
        float sum = lsum[r];
        #pragma unroll
        for (int off = 1; off < 16; off <<= 1)
            sum += __shfl_xor(sum, off, 64);
        if (ln == 0) Lp[wave * 16 + qd*4 + r] = sum;
    }
    _Float16* om = (_Float16*)KsB + (size_t)wave * 16 * 128;
    #pragma unroll
    for (int ht = 0; ht < 8; ht++)
        #pragma unroll
        for (int r = 0; r < 4; r++)
            om[(qd*4 + r) * 128 + ht*16 + ln] = (_Float16)O[ht][r];
    __syncthreads();

    // ---- 4-way merge (key quarters) + write: 64 rows x 16 thr, 8 h each ----
    {
        int row = tid >> 4, h0 = (tid & 15) * 8;
        int g = row >> 4, q = row & 15;
        float L = Lp[(g*4 + 0)*16 + q] + Lp[(g*4 + 1)*16 + q]
                + Lp[(g*4 + 2)*16 + q] + Lp[(g*4 + 3)*16 + q];
        float inv = 1.0f / L;
        const _Float16* p0 = (const _Float16*)KsB + (size_t)(g*4 + 0) * 2048 + q * 128 + h0;
        const _Float16* p1 = p0 + 2048;
        const _Float16* p2 = p1 + 2048;
        const _Float16* p3 = p2 + 2048;
        float* op = out + ((size_t)b * TT + qt * 64 + row) * HH + h0;
        #pragma unroll
        for (int i = 0; i < 2; i++) {
            float4 v;
            v.x = (((float)p0[i*4+0] + (float)p1[i*4+0]) + ((float)p2[i*4+0] + (float)p3[i*4+0])) * inv;
            v.y = (((float)p0[i*4+1] + (float)p1[i*4+1]) + ((float)p2[i*4+1] + (float)p3[i*4+1])) * inv;
            v.z = (((float)p0[i*4+2] + (float)p1[i*4+2]) + ((float)p2[i*4+2] + (float)p3[i*4+2])) * inv;
            v.w = (((float)p0[i*4+3] + (float)p1[i*4+3]) + ((float)p2[i*4+3] + (float)p3[i*4+3])) * inv;
            ((float4*)op)[i] = v;
        }
    }
    #undef STAGE
}

// ---------------------------------------------------------------------------
extern "C" void kernel_launch(void* const* d_in, const int* in_sizes, int n_in,
                              void* d_out, int out_size, void* d_ws, size_t ws_size,
                              hipStream_t stream) {
    const float* x  = (const float*)d_in[0];
    const float* Wq = (const float*)d_in[1];
    const float* Wk = (const float*)d_in[2];
    const float* Wv = (const float*)d_in[3];

    // workspace (u16): Wb [384][1024]; Q,K [16384][128]; Vt [8][128][VTP]
    unsigned short* Wb = (unsigned short*)d_ws;
    unsigned short* Qw = Wb + (size_t)3 * HH * CC;
    unsigned short* Kw = Qw + (size_t)BB * TT * HH;
    unsigned short* Vw = Kw + (size_t)BB * TT * HH;

    // 149 KB dynamic LDS for attn (>64 KB default cap)
    static bool attr_done = false;
    if (!attr_done) {
        hipFuncSetAttribute((const void*)attn,
                            hipFuncAttributeMaxDynamicSharedMemorySize, 152576);
        attr_done = true;
    }

    wconv<<<dim3(192), 256, 0, stream>>>(Wq, Wk, Wv, Wb);
    qkv_proj<<<dim3(256), 512, 0, stream>>>(x, Wb, Qw, Kw, Vw);
    attn<<<dim3(256), 1024, 152576, stream>>>(Qw, Kw, Vw, (float*)d_out);
}